// Round 13
// baseline (455.922 us; speedup 1.0000x reference)
//
#include <hip/hip_runtime.h>
#include <hip/hip_bf16.h>
#include <cstdint>
#include <cstddef>

#define LRELU(x, s) ((x) > 0.f ? (x) : (s) * (x))

typedef __attribute__((ext_vector_type(8))) short bf16x8;
typedef __attribute__((ext_vector_type(4))) float f32x4;

__device__ __forceinline__ float bflo(uint v) { return __uint_as_float(v << 16); }
__device__ __forceinline__ float bfhi(uint v) { return __uint_as_float(v & 0xffff0000u); }
__device__ __forceinline__ ushort f2bf(float f) {  // RTNE, finite inputs
  const uint u = __float_as_uint(f);
  return (ushort)((u + 0x7fffu + ((u >> 16) & 1u)) >> 16);
}
__device__ __forceinline__ float rl_f(float x, int j) {
  return __uint_as_float(__builtin_amdgcn_readlane(__float_as_uint(x), j));
}

// async global->LDS copy, 16 B per lane; LDS dest = wave-uniform base + lane*16.
__device__ __forceinline__ void async16(const ushort* g, ushort* l) {
  __builtin_amdgcn_global_load_lds(
      (const __attribute__((address_space(1))) unsigned int*)g,
      (__attribute__((address_space(3))) unsigned int*)l, 16, 0, 0);
}

// s_waitcnt immediates: vmcnt in [3:0], expcnt=7 (no wait), lgkmcnt=15 (no wait)
#define WAITCNT_VM(n) (0xF70 | (n))

// ---------------- 256-thread CSR exclusive scan (runs as a tail block of gemm1) --------
__device__ void scan_block256(const int* __restrict__ deg, int* __restrict__ rowptr,
                              int* __restrict__ cursor, int n) {
  __shared__ int swsum[4];
  __shared__ int carry_s;
  const int t = threadIdx.x;
  const int wv = t >> 6, lane = t & 63;
  if (t == 0) carry_s = 0;
  __syncthreads();
  for (int base = 0; base < n; base += 256) {
    const int i = base + t;
    const int v = (i < n) ? (deg[i] + 1) : 0;
    int sc = v;
#pragma unroll
    for (int off = 1; off < 64; off <<= 1) {
      const int u = __shfl_up(sc, off);
      if (lane >= off) sc += u;
    }
    if (lane == 63) swsum[wv] = sc;
    __syncthreads();
    if (t == 0) {
      int a = swsum[0];
      a += swsum[1]; swsum[1] = a;
      a += swsum[2]; swsum[2] = a;
      a += swsum[3]; swsum[3] = a;
    }
    __syncthreads();
    const int incl = sc + (wv == 0 ? 0 : swsum[wv - 1]) + carry_s;
    if (i < n) { rowptr[i + 1] = incl; cursor[i] = incl - v; }
    if (base == 0 && t == 0) rowptr[0] = 0;
    __syncthreads();
    if (t == 0) carry_s += swsum[3];
    __syncthreads();
  }
}

// ---------------- fused prep: x cast+pad (8-wide), 3x W transpose-cast, count_deg ------
__global__ __launch_bounds__(256) void prep_all(
    const float* __restrict__ x, ushort* __restrict__ xb,
    const float* __restrict__ W1, ushort* __restrict__ W1t,
    const float* __restrict__ W2, ushort* __restrict__ W2t,
    const float* __restrict__ W3, ushort* __restrict__ W3t,
    const int* __restrict__ edst, int* __restrict__ deg, int E,
    int N, int K1, int K1p, int nA, int nB, int nC, int nD) {
  __shared__ float tile[32][33];
  const int tid = threadIdx.x;
  int b = blockIdx.x;
  if (b < nA) {  // x: fp32 -> bf16, 8 elems/thread, K padding
    const int P8 = K1p >> 3;   // 164
    const long long idx = (long long)b * 256 + tid;
    if (idx < (long long)N * P8) {
      const int r = (int)(idx / P8);
      const int c = ((int)(idx - (long long)r * P8)) << 3;
      const float* p = x + (size_t)r * K1 + c;
      float v[8];
      if (c + 7 < K1) {
        const float4 a = *(const float4*)p;
        const float4 bq = *(const float4*)(p + 4);
        v[0] = a.x; v[1] = a.y; v[2] = a.z; v[3] = a.w;
        v[4] = bq.x; v[5] = bq.y; v[6] = bq.z; v[7] = bq.w;
      } else {
#pragma unroll
        for (int j = 0; j < 8; j++) v[j] = (c + j < K1) ? p[j] : 0.f;
      }
      uint4 o;
      o.x = (uint)f2bf(v[0]) | ((uint)f2bf(v[1]) << 16);
      o.y = (uint)f2bf(v[2]) | ((uint)f2bf(v[3]) << 16);
      o.z = (uint)f2bf(v[4]) | ((uint)f2bf(v[5]) << 16);
      o.w = (uint)f2bf(v[6]) | ((uint)f2bf(v[7]) << 16);
      *(uint4*)(xb + (size_t)r * K1p + c) = o;
    }
    return;
  }
  b -= nA;
  if (b < nB + nC + nD) {  // W transpose-casts
    const float* W; ushort* Wt; int K, Nn, Kp, tilesK;
    if (b < nB)           { W = W1; Wt = W1t; K = K1;   Nn = 512;  Kp = K1p;  tilesK = K1p / 32; }
    else if (b < nB + nC) { b -= nB; W = W2; Wt = W2t; K = 512;  Nn = 1024; Kp = 512;  tilesK = 16; }
    else                  { b -= nB + nC; W = W3; Wt = W3t; K = 1024; Nn = 128; Kp = 1024; tilesK = 32; }
    const int kt = (b % tilesK) * 32;
    const int nt = (b / tilesK) * 32;
    const int tx = tid & 31, ty = tid >> 5;
    for (int r = ty; r < 32; r += 8) {
      const int k = kt + r, nn = nt + tx;
      tile[r][tx] = (k < K && nn < Nn) ? W[(size_t)k * Nn + nn] : 0.f;
    }
    __syncthreads();
    for (int r = ty; r < 32; r += 8) {
      const int nn = nt + r, k = kt + tx;
      if (nn < Nn && k < Kp) Wt[(size_t)nn * Kp + k] = f2bf(tile[tx][r]);
    }
    return;
  }
  b -= nB + nC + nD;
  {  // count_deg (deg pre-zeroed by memset)
    const int t = b * 256 + tid;
    if (t < E) atomicAdd(&deg[edst[t]], 1);
  }
}

// ---------------- bf16 MFMA GEMM ------------------------------------------------------
// BUF3=true : 3-buffer, single barrier per K-step (48KB LDS, 3 blocks/CU).
// BUF3=false: 2-buffer, two barriers per K-step (32KB LDS, 5 blocks/CU) — layer 2.
// Blocks >= gemmBlocks run the CSR scan (layer-1 launch only, 1 block; hidden under GEMM).
template <int TM, int TAG, bool BUF3>
__global__ __launch_bounds__(256) void gemm_bf16(
    const ushort* __restrict__ A, const ushort* __restrict__ Bt, ushort* __restrict__ C,
    int M, int N, int Kp, int gemmBlocks,
    const int* __restrict__ deg, int* __restrict__ rowptr, int* __restrict__ cursor,
    int scanN) {
  constexpr int MI = TM / 32;               // mi-tiles per wave (4 or 2)
  constexpr int LPG = (TM == 128) ? 4 : 3;  // loads per group per lane
  constexpr int NBUF = BUF3 ? 3 : 2;
  __shared__ ushort sA[NBUF * TM * 32];
  __shared__ ushort sB[NBUF * 128 * 32];
  const int tid = threadIdx.x;
  const int wave = tid >> 6;
  const int lane = tid & 63;

  if (blockIdx.x >= gemmBlocks) {  // CSR scan rides this launch (deg from prior launch)
    scan_block256(deg, rowptr, cursor, scanN);
    return;
  }

  const int tilesN = N >> 7;
  // bijective XCD-aware remap (works sharing an A row-panel land on one XCD)
  const int nwg = gemmBlocks;
  const int q8 = nwg >> 3, r8 = nwg & 7;
  const int xcd = blockIdx.x & 7;
  const int lid = blockIdx.x >> 3;
  const int wg = (xcd < r8 ? xcd * (q8 + 1) : r8 * (q8 + 1) + (xcd - r8) * q8) + lid;
  const int bx = wg % tilesN;
  const int by = wg / tilesN;
  const int wrow = (wave >> 1) * (TM / 2);
  const int wcol = (wave & 1) * 64;
  const int quad = lane >> 4;
  const int ml = lane & 15;

  const int seg = (((lane & 3) ^ ((lane >> 3) & 3)) * 8);
  const int rB0 = wave * 32 + (lane >> 2);
  const int gB0 = bx * 128 + rB0;
  const ushort* pB0 = Bt + (size_t)gB0 * Kp + seg;
  const ushort* pB1 = Bt + (size_t)(gB0 + 16) * Kp + seg;
  ushort* lB0 = &sB[(wave * 32) * 32];
  ushort* lB1 = &sB[(wave * 32 + 16) * 32];
  const ushort *pA0, *pA1;
  ushort *lA0, *lA1;
  if constexpr (TM == 128) {
    const int r0 = wave * 32 + (lane >> 2);
    pA0 = A + (size_t)min(by * TM + r0, M - 1) * Kp + seg;
    pA1 = A + (size_t)min(by * TM + r0 + 16, M - 1) * Kp + seg;
    lA0 = &sA[(wave * 32) * 32];
    lA1 = &sA[(wave * 32 + 16) * 32];
  } else {
    const int r0 = wave * 16 + (lane >> 2);
    pA0 = A + (size_t)min(by * TM + r0, M - 1) * Kp + seg;
    pA1 = nullptr;
    lA0 = &sA[(wave * 16) * 32];
    lA1 = nullptr;
  }

  const int nIter = Kp >> 5;
  auto issue = [&](int it, int p) {
    const int k0 = it << 5;
    const int oa = p * TM * 32;
    const int ob_ = p * 128 * 32;
    async16(pA0 + k0, lA0 + oa);
    if constexpr (TM == 128) async16(pA1 + k0, lA1 + oa);
    async16(pB0 + k0, lB0 + ob_);
    async16(pB1 + k0, lB1 + ob_);
  };

  f32x4 acc[MI][4];
#pragma unroll
  for (int mi = 0; mi < MI; mi++)
#pragma unroll
    for (int ni = 0; ni < 4; ni++)
#pragma unroll
      for (int e = 0; e < 4; e++) acc[mi][ni][e] = 0.f;

  const int rq = (quad ^ ((ml >> 1) & 3)) * 8;  // un-swizzle for fragment reads

  issue(0, 0);
  if (nIter > 1) issue(1, 1);
  int b = 0;
  for (int it = 0; it < nIter; ++it) {
    if (it + 1 < nIter) __builtin_amdgcn_s_waitcnt(WAITCNT_VM(LPG));
    else __builtin_amdgcn_s_waitcnt(WAITCNT_VM(0));
    __builtin_amdgcn_s_barrier();
    if constexpr (BUF3) {
      if (it + 2 < nIter) {
        const int b2 = (b + 2 >= 3) ? b - 1 : b + 2;  // = (it+2)%3, holds tile it-1 (free)
        issue(it + 2, b2);
      }
    }
    const ushort* bA = &sA[b * TM * 32];
    const ushort* bB = &sB[b * 128 * 32];
    bf16x8 af[MI], bfr[4];
#pragma unroll
    for (int mi = 0; mi < MI; mi++)
      af[mi] = *(const bf16x8*)&bA[(wrow + mi * 16 + ml) * 32 + rq];
#pragma unroll
    for (int ni = 0; ni < 4; ni++)
      bfr[ni] = *(const bf16x8*)&bB[(wcol + ni * 16 + ml) * 32 + rq];
#pragma unroll
    for (int mi = 0; mi < MI; mi++)
#pragma unroll
      for (int ni = 0; ni < 4; ni++)
        acc[mi][ni] = __builtin_amdgcn_mfma_f32_16x16x32_bf16(af[mi], bfr[ni], acc[mi][ni], 0, 0, 0);
    if constexpr (!BUF3) {
      if (it + 2 < nIter) {
        __builtin_amdgcn_s_barrier();  // all waves done reading buf b
        issue(it + 2, b);
      }
      b ^= 1;
    } else {
      b = (b + 1 == 3) ? 0 : b + 1;
    }
  }

  // C write (bf16)
#pragma unroll
  for (int mi = 0; mi < MI; mi++) {
#pragma unroll
    for (int r = 0; r < 4; r++) {
      const int row = by * TM + wrow + mi * 16 + quad * 4 + r;
      if (row < M) {
#pragma unroll
        for (int ni = 0; ni < 4; ni++) {
          const int col = bx * 128 + wcol + ni * 16 + ml;
          C[(size_t)row * N + col] = f2bf(acc[mi][ni][r]);
        }
      }
    }
  }
}

// ---------------- attention dots, h-side: asb/adb[n,h] = dot(hb[n,h*C:..], AS/AD[h]) ---
// Blocks >= dotsBlocks run scatter_edges (layer-1 launch only; scan in prior launch).
template <int H, int C>
__global__ __launch_bounds__(256) void att_dots(
    const ushort* __restrict__ hb, const float* __restrict__ AS,
    const float* __restrict__ AD, float* __restrict__ asb, float* __restrict__ adb,
    int Nn, int dotsBlocks,
    const int* __restrict__ esrc, const int* __restrict__ edst, int E, int Etot,
    int* __restrict__ cursor, int* __restrict__ csr_src) {
  constexpr int HC = H * C;
  constexpr int EPL = HC / 64;
  constexpr int S = C / EPL;
  const int lane = threadIdx.x & 63;
  if (blockIdx.x >= dotsBlocks) {  // scatter
    const int t = (blockIdx.x - dotsBlocks) * 256 + threadIdx.x;
    if (t >= Etot) return;
    int s, d;
    if (t < E) { s = esrc[t]; d = edst[t]; } else { s = t - E; d = s; }
    const int pos = atomicAdd(&cursor[d], 1);
    csr_src[pos] = s;
    return;
  }
  const int n = blockIdx.x * 4 + (threadIdx.x >> 6);
  if (n >= Nn) return;
  const int head = lane / S;
  const int cbase = (lane % S) * EPL;
  const ushort* row = hb + (size_t)n * HC + lane * EPL;
  const float* as_h = AS + head * C;
  const float* ad_h = AD + head * C;
  float ps = 0.f, pd = 0.f;
#pragma unroll
  for (int j = 0; j < EPL; j += 2) {
    const uint v = *(const uint*)(row + j);
    const float lo = bflo(v), hi = bfhi(v);
    ps += lo * as_h[cbase + j] + hi * as_h[cbase + j + 1];
    pd += lo * ad_h[cbase + j] + hi * ad_h[cbase + j + 1];
  }
#pragma unroll
  for (int off = 1; off < S; off <<= 1) {
    ps += __shfl_xor(ps, off);
    pd += __shfl_xor(pd, off);
  }
  if ((lane % S) == 0) {
    asb[n * H + head] = ps;
    adb[n * H + head] = pd;
  }
}

// ---------------- wave-per-node softmax-weighted gather aggregate (output-space) -------
template <int H, int C>
__global__ __launch_bounds__(256) void gat_agg_wave(
    const ushort* __restrict__ hb, const int* __restrict__ rowptr,
    const int* __restrict__ csr_src, const float* __restrict__ a_s,
    const float* __restrict__ a_d, const float* __restrict__ bias,
    ushort* __restrict__ outb, float act_slope, int Nn) {
  constexpr int HC = H * C;
  constexpr int NU = HC / 2;
  constexpr int UPT = NU / 256;       // uint4 per lane
  constexpr int GRP = (UPT == 2) ? 4 : 8;
  const int n = blockIdx.x * 4 + (threadIdx.x >> 6);
  const int lane = threadIdx.x & 63;
  if (n >= Nn) return;
  float ad_n[H];
#pragma unroll
  for (int h = 0; h < H; h++) ad_n[h] = a_d[n * H + h];
  const int start = rowptr[n], end = rowptr[n + 1];
  f32x4 acc[UPT][2];
#pragma unroll
  for (int q = 0; q < UPT; q++)
#pragma unroll
    for (int u = 0; u < 2; u++)
#pragma unroll
      for (int e = 0; e < 4; e++) acc[q][u][e] = 0.f;
  float den[H];
#pragma unroll
  for (int h = 0; h < H; h++) den[h] = 0.f;

  for (int base = start; base < end; base += 64) {
    const int cnt = min(64, end - base);
    int s = 0;
    float w[H];
#pragma unroll
    for (int h = 0; h < H; h++) w[h] = 0.f;
    if (lane < cnt) {
      s = csr_src[base + lane];
      float asv[H];
      if constexpr (H == 4) {
        const float4 t4 = *(const float4*)(a_s + s * 4);
        asv[0] = t4.x; asv[1] = t4.y; asv[2] = t4.z; asv[3] = t4.w;
      } else {
        asv[0] = a_s[s];
      }
#pragma unroll
      for (int h = 0; h < H; h++) {
        float lg = asv[h] + ad_n[h];
        lg = LRELU(lg, 0.2f);
        w[h] = __expf(lg);
        den[h] += w[h];
      }
    }
    const int cntg = cnt & ~(GRP - 1);
    int j = 0;
    for (; j < cntg; j += GRP) {
      uint4 v[GRP][UPT];
#pragma unroll
      for (int g = 0; g < GRP; g++) {
        const int sj = __builtin_amdgcn_readlane(s, j + g);
        const uint4* hp = (const uint4*)(hb + (size_t)sj * HC);
#pragma unroll
        for (int q = 0; q < UPT; q++) v[g][q] = hp[q * 64 + lane];
      }
#pragma unroll
      for (int g = 0; g < GRP; g++) {
        float wj[H];
#pragma unroll
        for (int h = 0; h < H; h++) wj[h] = rl_f(w[h], j + g);
#pragma unroll
        for (int q = 0; q < UPT; q++) {
          const int e0 = q * 512 + 8 * lane;
          const float wq = wj[e0 / C];
          acc[q][0][0] += wq * bflo(v[g][q].x);
          acc[q][0][1] += wq * bfhi(v[g][q].x);
          acc[q][0][2] += wq * bflo(v[g][q].y);
          acc[q][0][3] += wq * bfhi(v[g][q].y);
          acc[q][1][0] += wq * bflo(v[g][q].z);
          acc[q][1][1] += wq * bfhi(v[g][q].z);
          acc[q][1][2] += wq * bflo(v[g][q].w);
          acc[q][1][3] += wq * bfhi(v[g][q].w);
        }
      }
    }
    for (; j < cnt; j++) {
      const int sj = __builtin_amdgcn_readlane(s, j);
      float wj[H];
#pragma unroll
      for (int h = 0; h < H; h++) wj[h] = rl_f(w[h], j);
      const uint4* hp = (const uint4*)(hb + (size_t)sj * HC);
#pragma unroll
      for (int q = 0; q < UPT; q++) {
        const int e0 = q * 512 + 8 * lane;
        const uint4 v = hp[q * 64 + lane];
        const float wq = wj[e0 / C];
        acc[q][0][0] += wq * bflo(v.x);
        acc[q][0][1] += wq * bfhi(v.x);
        acc[q][0][2] += wq * bflo(v.y);
        acc[q][0][3] += wq * bfhi(v.y);
        acc[q][1][0] += wq * bflo(v.z);
        acc[q][1][1] += wq * bfhi(v.z);
        acc[q][1][2] += wq * bflo(v.w);
        acc[q][1][3] += wq * bfhi(v.w);
      }
    }
  }
#pragma unroll
  for (int h = 0; h < H; h++) {
#pragma unroll
    for (int off = 1; off < 64; off <<= 1) den[h] += __shfl_xor(den[h], off);
    den[h] = 1.f / den[h];
  }
#pragma unroll
  for (int q = 0; q < UPT; q++) {
    const int e0 = q * 512 + 8 * lane;
    const float iv = den[e0 / C];
    const float4 ba = *(const float4*)(bias + e0);
    const float4 bb = *(const float4*)(bias + e0 + 4);
    const float o0 = LRELU(acc[q][0][0] * iv + ba.x, act_slope);
    const float o1 = LRELU(acc[q][0][1] * iv + ba.y, act_slope);
    const float o2 = LRELU(acc[q][0][2] * iv + ba.z, act_slope);
    const float o3 = LRELU(acc[q][0][3] * iv + ba.w, act_slope);
    const float o4 = LRELU(acc[q][1][0] * iv + bb.x, act_slope);
    const float o5 = LRELU(acc[q][1][1] * iv + bb.y, act_slope);
    const float o6 = LRELU(acc[q][1][2] * iv + bb.z, act_slope);
    const float o7 = LRELU(acc[q][1][3] * iv + bb.w, act_slope);
    uint4 o;
    o.x = (uint)f2bf(o0) | ((uint)f2bf(o1) << 16);
    o.y = (uint)f2bf(o2) | ((uint)f2bf(o3) << 16);
    o.z = (uint)f2bf(o4) | ((uint)f2bf(o5) << 16);
    o.w = (uint)f2bf(o6) | ((uint)f2bf(o7) << 16);
    ((uint4*)outb)[(size_t)n * (NU / 4) + q * 64 + lane] = o;
  }
}

// ---------------- layer-3 aggregate (H=1,C=128) fused with head MLP ------------------
__global__ __launch_bounds__(256) void gat_agg3_mlp(
    const ushort* __restrict__ hb, const int* __restrict__ rowptr,
    const int* __restrict__ csr_src, const float* __restrict__ a_s,
    const float* __restrict__ a_d, const float* __restrict__ b3,
    const float* __restrict__ pw, const float* __restrict__ pb,
    const float* __restrict__ f1w, const float* __restrict__ f1b,
    const float* __restrict__ f2w, const float* __restrict__ f2b,
    float* __restrict__ out, int Nn) {
  __shared__ float sx[4][128];
  __shared__ float s1[4][16];
  __shared__ float s2[4][32];
  const int w = threadIdx.x >> 6;
  const int lane = threadIdx.x & 63;
  const int n = blockIdx.x * 4 + w;
  if (n >= Nn) return;
  const float ad_n = a_d[n];
  const int start = rowptr[n], end = rowptr[n + 1];
  float2 acc = make_float2(0.f, 0.f);
  float den = 0.f;
  for (int base = start; base < end; base += 64) {
    const int cnt = min(64, end - base);
    int s = 0;
    float wv_ = 0.f;
    if (lane < cnt) {
      s = csr_src[base + lane];
      float lg = a_s[s] + ad_n;
      lg = LRELU(lg, 0.2f);
      wv_ = __expf(lg);
      den += wv_;
    }
    const int cntg = cnt & ~7;
    int j = 0;
    for (; j < cntg; j += 8) {
      uint v[8];
      float wj[8];
#pragma unroll
      for (int g = 0; g < 8; g++) {
        const int sj = __builtin_amdgcn_readlane(s, j + g);
        v[g] = ((const uint*)(hb + (size_t)sj * 128))[lane];
        wj[g] = rl_f(wv_, j + g);
      }
#pragma unroll
      for (int g = 0; g < 8; g++) {
        acc.x += wj[g] * bflo(v[g]);
        acc.y += wj[g] * bfhi(v[g]);
      }
    }
    for (; j < cnt; j++) {
      const int sj = __builtin_amdgcn_readlane(s, j);
      const float wj = rl_f(wv_, j);
      const uint v = ((const uint*)(hb + (size_t)sj * 128))[lane];
      acc.x += wj * bflo(v);
      acc.y += wj * bfhi(v);
    }
  }
#pragma unroll
  for (int off = 1; off < 64; off <<= 1) den += __shfl_xor(den, off);
  const float iv = 1.f / den;
  sx[w][2 * lane]     = LRELU(acc.x * iv + b3[2 * lane], 0.15f);
  sx[w][2 * lane + 1] = LRELU(acc.y * iv + b3[2 * lane + 1], 0.15f);
  {
    const int o = lane & 15, p = lane >> 4;
    float a = 0.f;
#pragma unroll
    for (int c = 0; c < 32; c++) a += sx[w][p * 32 + c] * pw[(p * 32 + c) * 16 + o];
    a += __shfl_xor(a, 16);
    a += __shfl_xor(a, 32);
    if (lane < 16) s1[w][o] = a + pb[o];
  }
  {
    const int o = lane & 31, p = lane >> 5;
    float a = 0.f;
#pragma unroll
    for (int c = 0; c < 8; c++) a += s1[w][p * 8 + c] * f1w[(p * 8 + c) * 32 + o];
    a += __shfl_xor(a, 32);
    if (lane < 32) s2[w][o] = LRELU(a + f1b[o], 0.15f);
  }
  {
    const int o = lane & 1, p = lane >> 1;
    float a = s2[w][p] * f2w[p * 2 + o];
    a += __shfl_xor(a, 2);
    a += __shfl_xor(a, 4);
    a += __shfl_xor(a, 8);
    a += __shfl_xor(a, 16);
    a += __shfl_xor(a, 32);
    if (lane < 2) out[(size_t)n * 2 + o] = a + f2b[o];
  }
}

extern "C" void kernel_launch(void* const* d_in, const int* in_sizes, int n_in,
                              void* d_out, int out_size, void* d_ws, size_t ws_size,
                              hipStream_t stream) {
  const float* x   = (const float*)d_in[0];
  const int* ei    = (const int*)d_in[1];
  const float* W1  = (const float*)d_in[2];
  const float* as1 = (const float*)d_in[3];
  const float* ad1 = (const float*)d_in[4];
  const float* b1  = (const float*)d_in[5];
  const float* W2  = (const float*)d_in[6];
  const float* as2 = (const float*)d_in[7];
  const float* ad2 = (const float*)d_in[8];
  const float* b2  = (const float*)d_in[9];
  const float* W3  = (const float*)d_in[10];
  const float* as3 = (const float*)d_in[11];
  const float* ad3 = (const float*)d_in[12];
  const float* b3  = (const float*)d_in[13];
  const float* pw  = (const float*)d_in[14];
  const float* pb  = (const float*)d_in[15];
  const float* f1w = (const float*)d_in[16];
  const float* f1b = (const float*)d_in[17];
  const float* f2w = (const float*)d_in[18];
  const float* f2b = (const float*)d_in[19];
  float* out = (float*)d_out;

  const int N = in_sizes[0] / 1287;   // 20000
  const int E = in_sizes[1] / 2;      // 160000
  const int Etot = E + N;
  const int* esrc = ei;
  const int* edst = ei + E;
  const int K1 = 1287, K1p = 1312;

  char* ws = (char*)d_ws;
  size_t off = 0;
  auto alloc = [&](size_t bytes) -> void* {
    void* p = ws + off;
    off = (off + bytes + 255) & ~(size_t)255;
    return p;
  };
  ushort* hb  = (ushort*)alloc((size_t)N * 1024 * 2);
  ushort* ob  = (ushort*)alloc((size_t)N * 1024 * 2);
  ushort* xb  = (ushort*)alloc((size_t)N * K1p * 2);
  ushort* W1t = (ushort*)alloc((size_t)512 * K1p * 2);
  ushort* W2t = (ushort*)alloc((size_t)1024 * 512 * 2);
  ushort* W3t = (ushort*)alloc((size_t)128 * 1024 * 2);
  float* av   = (float*)alloc((size_t)N * 8 * sizeof(float));  // a_s then a_d
  int* deg    = (int*)alloc((size_t)N * sizeof(int));
  int* rowptr = (int*)alloc((size_t)(N + 1) * sizeof(int));
  int* cursor = (int*)alloc((size_t)N * sizeof(int));
  int* csr    = (int*)alloc((size_t)Etot * sizeof(int));
  float* asb = av;
  float* adb = av + (size_t)N * 4;

  // ---- prep: deg zero (memset) + fused cast/transpose/count_deg ----
  hipMemsetAsync(deg, 0, (size_t)N * sizeof(int), stream);
  const int nA = (int)(((long long)N * (K1p / 8) + 255) / 256);  // 12813
  const int nB = (K1p / 32) * (512 / 32);                        // 656
  const int nC = (512 / 32) * (1024 / 32);                       // 512
  const int nD = (1024 / 32) * (128 / 32);                       // 128
  const int nCnt = (E + 255) / 256;                              // 625
  prep_all<<<nA + nB + nC + nD + nCnt, 256, 0, stream>>>(
      x, xb, W1, W1t, W2, W2t, W3, W3t,
      edst, deg, E, N, K1, K1p, nA, nB, nC, nD);

  const int tilesM = (N + 127) / 128;    // 157
  const int tilesM64 = (N + 63) / 64;    // 313
  const int nodeBlocks = (N + 3) / 4;    // 5000
  const int scatB = (Etot + 255) / 256;  // 704

  // ---- layer 1: [gemm1 || scan] -> [dots1 || scatter] -> agg1 ----
  {
    const int g = tilesM * 4;  // 628 gemm blocks + 1 scan block (hidden under GEMM)
    gemm_bf16<128, 1, true><<<g + 1, 256, 0, stream>>>(
        xb, W1t, hb, N, 512, K1p, g, deg, rowptr, cursor, N);
    att_dots<4, 128><<<nodeBlocks + scatB, 256, 0, stream>>>(
        hb, as1, ad1, asb, adb, N, nodeBlocks, esrc, edst, E, Etot, cursor, csr);
    gat_agg_wave<4, 128><<<nodeBlocks, 256, 0, stream>>>(hb, rowptr, csr, asb, adb,
                                                         b1, ob, 0.15f, N);
  }
  // ---- layer 2: gemm2 (2-buffer) -> dots2 -> agg2 ----
  {
    const int g = tilesM * 8;  // 1256
    gemm_bf16<128, 2, false><<<g, 256, 0, stream>>>(
        ob, W2t, hb, N, 1024, 512, g, nullptr, nullptr, nullptr, 0);
    att_dots<4, 256><<<nodeBlocks, 256, 0, stream>>>(
        hb, as2, ad2, asb, adb, N, nodeBlocks, nullptr, nullptr, 0, 0, nullptr, nullptr);
    gat_agg_wave<4, 256><<<nodeBlocks, 256, 0, stream>>>(hb, rowptr, csr, asb, adb,
                                                         b2, ob, 0.15f, N);
  }
  // ---- layer 3: gemm3 -> dots3 -> agg3 + MLP ----
  {
    gemm_bf16<64, 3, true><<<tilesM64, 256, 0, stream>>>(
        ob, W3t, hb, N, 128, 1024, tilesM64, nullptr, nullptr, nullptr, 0);
    att_dots<1, 128><<<nodeBlocks, 256, 0, stream>>>(
        hb, as3, ad3, asb, adb, N, nodeBlocks, nullptr, nullptr, 0, 0, nullptr, nullptr);
    gat_agg3_mlp<<<nodeBlocks, 256, 0, stream>>>(hb, rowptr, csr, asb, adb, b3,
                                                 pw, pb, f1w, f1b, f2w, f2b, out, N);
  }
}

// Round 14
// 450.026 us; speedup vs baseline: 1.0131x; 1.0131x over previous
//
#include <hip/hip_runtime.h>
#include <hip/hip_bf16.h>
#include <cstdint>
#include <cstddef>

#define LRELU(x, s) ((x) > 0.f ? (x) : (s) * (x))

typedef __attribute__((ext_vector_type(8))) short bf16x8;
typedef __attribute__((ext_vector_type(4))) float f32x4;

__device__ __forceinline__ float bflo(uint v) { return __uint_as_float(v << 16); }
__device__ __forceinline__ float bfhi(uint v) { return __uint_as_float(v & 0xffff0000u); }
__device__ __forceinline__ ushort f2bf(float f) {  // RTNE, finite inputs
  const uint u = __float_as_uint(f);
  return (ushort)((u + 0x7fffu + ((u >> 16) & 1u)) >> 16);
}
__device__ __forceinline__ float rl_f(float x, int j) {
  return __uint_as_float(__builtin_amdgcn_readlane(__float_as_uint(x), j));
}

// async global->LDS copy, 16 B per lane; LDS dest = wave-uniform base + lane*16.
__device__ __forceinline__ void async16(const ushort* g, ushort* l) {
  __builtin_amdgcn_global_load_lds(
      (const __attribute__((address_space(1))) unsigned int*)g,
      (__attribute__((address_space(3))) unsigned int*)l, 16, 0, 0);
}

// s_waitcnt immediates: vmcnt in [3:0], expcnt=7 (no wait), lgkmcnt=15 (no wait)
#define WAITCNT_VM(n) (0xF70 | (n))

// ---------------- fused prep: x cast+pad (8-wide), 3x W transpose-cast, count_deg ------
__global__ __launch_bounds__(256) void prep_all(
    const float* __restrict__ x, ushort* __restrict__ xb,
    const float* __restrict__ W1, ushort* __restrict__ W1t,
    const float* __restrict__ W2, ushort* __restrict__ W2t,
    const float* __restrict__ W3, ushort* __restrict__ W3t,
    const int* __restrict__ edst, int* __restrict__ deg, int E,
    int N, int K1, int K1p, int nA, int nB, int nC, int nD) {
  __shared__ float tile[32][33];
  const int tid = threadIdx.x;
  int b = blockIdx.x;
  if (b < nA) {  // x: fp32 -> bf16, 8 elems/thread, K padding
    const int P8 = K1p >> 3;   // 164
    const long long idx = (long long)b * 256 + tid;
    if (idx < (long long)N * P8) {
      const int r = (int)(idx / P8);
      const int c = ((int)(idx - (long long)r * P8)) << 3;
      const float* p = x + (size_t)r * K1 + c;
      float v[8];
      if (c + 7 < K1) {
        const float4 a = *(const float4*)p;
        const float4 bq = *(const float4*)(p + 4);
        v[0] = a.x; v[1] = a.y; v[2] = a.z; v[3] = a.w;
        v[4] = bq.x; v[5] = bq.y; v[6] = bq.z; v[7] = bq.w;
      } else {
#pragma unroll
        for (int j = 0; j < 8; j++) v[j] = (c + j < K1) ? p[j] : 0.f;
      }
      uint4 o;
      o.x = (uint)f2bf(v[0]) | ((uint)f2bf(v[1]) << 16);
      o.y = (uint)f2bf(v[2]) | ((uint)f2bf(v[3]) << 16);
      o.z = (uint)f2bf(v[4]) | ((uint)f2bf(v[5]) << 16);
      o.w = (uint)f2bf(v[6]) | ((uint)f2bf(v[7]) << 16);
      *(uint4*)(xb + (size_t)r * K1p + c) = o;
    }
    return;
  }
  b -= nA;
  if (b < nB + nC + nD) {  // W transpose-casts
    const float* W; ushort* Wt; int K, Nn, Kp, tilesK;
    if (b < nB)           { W = W1; Wt = W1t; K = K1;   Nn = 512;  Kp = K1p;  tilesK = K1p / 32; }
    else if (b < nB + nC) { b -= nB; W = W2; Wt = W2t; K = 512;  Nn = 1024; Kp = 512;  tilesK = 16; }
    else                  { b -= nB + nC; W = W3; Wt = W3t; K = 1024; Nn = 128; Kp = 1024; tilesK = 32; }
    const int kt = (b % tilesK) * 32;
    const int nt = (b / tilesK) * 32;
    const int tx = tid & 31, ty = tid >> 5;
    for (int r = ty; r < 32; r += 8) {
      const int k = kt + r, nn = nt + tx;
      tile[r][tx] = (k < K && nn < Nn) ? W[(size_t)k * Nn + nn] : 0.f;
    }
    __syncthreads();
    for (int r = ty; r < 32; r += 8) {
      const int nn = nt + r, k = kt + tx;
      if (nn < Nn && k < Kp) Wt[(size_t)nn * Kp + k] = f2bf(tile[tx][r]);
    }
    return;
  }
  b -= nB + nC + nD;
  {  // count_deg (deg pre-zeroed by memset)
    const int t = b * 256 + tid;
    if (t < E) atomicAdd(&deg[edst[t]], 1);
  }
}

// ---------------- bf16 MFMA GEMM ------------------------------------------------------
// BUF3=true : 3-buffer, single barrier per K-step (48KB LDS, 3 blocks/CU).
// BUF3=false: 2-buffer, two barriers per K-step (32KB LDS, 5 blocks/CU) — layer 2.
template <int TM, int TAG, bool BUF3>
__global__ __launch_bounds__(256) void gemm_bf16(
    const ushort* __restrict__ A, const ushort* __restrict__ Bt, ushort* __restrict__ C,
    int M, int N, int Kp, int gemmBlocks) {
  constexpr int MI = TM / 32;               // mi-tiles per wave (4 or 2)
  constexpr int LPG = (TM == 128) ? 4 : 3;  // loads per group per lane
  constexpr int NBUF = BUF3 ? 3 : 2;
  __shared__ ushort sA[NBUF * TM * 32];
  __shared__ ushort sB[NBUF * 128 * 32];
  const int tid = threadIdx.x;
  const int wave = tid >> 6;
  const int lane = tid & 63;

  const int tilesN = N >> 7;
  // bijective XCD-aware remap (works sharing an A row-panel land on one XCD)
  const int nwg = gemmBlocks;
  const int q8 = nwg >> 3, r8 = nwg & 7;
  const int xcd = blockIdx.x & 7;
  const int lid = blockIdx.x >> 3;
  const int wg = (xcd < r8 ? xcd * (q8 + 1) : r8 * (q8 + 1) + (xcd - r8) * q8) + lid;
  const int bx = wg % tilesN;
  const int by = wg / tilesN;
  const int wrow = (wave >> 1) * (TM / 2);
  const int wcol = (wave & 1) * 64;
  const int quad = lane >> 4;
  const int ml = lane & 15;

  const int seg = (((lane & 3) ^ ((lane >> 3) & 3)) * 8);
  const int rB0 = wave * 32 + (lane >> 2);
  const int gB0 = bx * 128 + rB0;
  const ushort* pB0 = Bt + (size_t)gB0 * Kp + seg;
  const ushort* pB1 = Bt + (size_t)(gB0 + 16) * Kp + seg;
  ushort* lB0 = &sB[(wave * 32) * 32];
  ushort* lB1 = &sB[(wave * 32 + 16) * 32];
  const ushort *pA0, *pA1;
  ushort *lA0, *lA1;
  if constexpr (TM == 128) {
    const int r0 = wave * 32 + (lane >> 2);
    pA0 = A + (size_t)min(by * TM + r0, M - 1) * Kp + seg;
    pA1 = A + (size_t)min(by * TM + r0 + 16, M - 1) * Kp + seg;
    lA0 = &sA[(wave * 32) * 32];
    lA1 = &sA[(wave * 32 + 16) * 32];
  } else {
    const int r0 = wave * 16 + (lane >> 2);
    pA0 = A + (size_t)min(by * TM + r0, M - 1) * Kp + seg;
    pA1 = nullptr;
    lA0 = &sA[(wave * 16) * 32];
    lA1 = nullptr;
  }

  const int nIter = Kp >> 5;
  auto issue = [&](int it, int p) {
    const int k0 = it << 5;
    const int oa = p * TM * 32;
    const int ob_ = p * 128 * 32;
    async16(pA0 + k0, lA0 + oa);
    if constexpr (TM == 128) async16(pA1 + k0, lA1 + oa);
    async16(pB0 + k0, lB0 + ob_);
    async16(pB1 + k0, lB1 + ob_);
  };

  f32x4 acc[MI][4];
#pragma unroll
  for (int mi = 0; mi < MI; mi++)
#pragma unroll
    for (int ni = 0; ni < 4; ni++)
#pragma unroll
      for (int e = 0; e < 4; e++) acc[mi][ni][e] = 0.f;

  const int rq = (quad ^ ((ml >> 1) & 3)) * 8;  // un-swizzle for fragment reads

  issue(0, 0);
  if (nIter > 1) issue(1, 1);
  int b = 0;
  for (int it = 0; it < nIter; ++it) {
    if (it + 1 < nIter) __builtin_amdgcn_s_waitcnt(WAITCNT_VM(LPG));
    else __builtin_amdgcn_s_waitcnt(WAITCNT_VM(0));
    __builtin_amdgcn_s_barrier();
    if constexpr (BUF3) {
      if (it + 2 < nIter) {
        const int b2 = (b + 2 >= 3) ? b - 1 : b + 2;  // = (it+2)%3, holds tile it-1 (free)
        issue(it + 2, b2);
      }
    }
    const ushort* bA = &sA[b * TM * 32];
    const ushort* bB = &sB[b * 128 * 32];
    bf16x8 af[MI], bfr[4];
#pragma unroll
    for (int mi = 0; mi < MI; mi++)
      af[mi] = *(const bf16x8*)&bA[(wrow + mi * 16 + ml) * 32 + rq];
#pragma unroll
    for (int ni = 0; ni < 4; ni++)
      bfr[ni] = *(const bf16x8*)&bB[(wcol + ni * 16 + ml) * 32 + rq];
#pragma unroll
    for (int mi = 0; mi < MI; mi++)
#pragma unroll
      for (int ni = 0; ni < 4; ni++)
        acc[mi][ni] = __builtin_amdgcn_mfma_f32_16x16x32_bf16(af[mi], bfr[ni], acc[mi][ni], 0, 0, 0);
    if constexpr (!BUF3) {
      if (it + 2 < nIter) {
        __builtin_amdgcn_s_barrier();  // all waves done reading buf b
        issue(it + 2, b);
      }
      b ^= 1;
    } else {
      b = (b + 1 == 3) ? 0 : b + 1;
    }
  }

  // C write (bf16)
#pragma unroll
  for (int mi = 0; mi < MI; mi++) {
#pragma unroll
    for (int r = 0; r < 4; r++) {
      const int row = by * TM + wrow + mi * 16 + quad * 4 + r;
      if (row < M) {
#pragma unroll
        for (int ni = 0; ni < 4; ni++) {
          const int col = bx * 128 + wcol + ni * 16 + ml;
          C[(size_t)row * N + col] = f2bf(acc[mi][ni][r]);
        }
      }
    }
  }
}

// ---------------- attention dots, h-side: asb/adb[n,h] = dot(hb[n,h*C:..], AS/AD[h]) ---
// Blocks >= dotsBlocks run scatter_edges (layer-1 launch only; scan in prior launch).
template <int H, int C>
__global__ __launch_bounds__(256) void att_dots(
    const ushort* __restrict__ hb, const float* __restrict__ AS,
    const float* __restrict__ AD, float* __restrict__ asb, float* __restrict__ adb,
    int Nn, int dotsBlocks,
    const int* __restrict__ esrc, const int* __restrict__ edst, int E, int Etot,
    int* __restrict__ cursor, int* __restrict__ csr_src) {
  constexpr int HC = H * C;
  constexpr int EPL = HC / 64;
  constexpr int S = C / EPL;
  const int lane = threadIdx.x & 63;
  if (blockIdx.x >= dotsBlocks) {  // scatter
    const int t = (blockIdx.x - dotsBlocks) * 256 + threadIdx.x;
    if (t >= Etot) return;
    int s, d;
    if (t < E) { s = esrc[t]; d = edst[t]; } else { s = t - E; d = s; }
    const int pos = atomicAdd(&cursor[d], 1);
    csr_src[pos] = s;
    return;
  }
  const int n = blockIdx.x * 4 + (threadIdx.x >> 6);
  if (n >= Nn) return;
  const int head = lane / S;
  const int cbase = (lane % S) * EPL;
  const ushort* row = hb + (size_t)n * HC + lane * EPL;
  const float* as_h = AS + head * C;
  const float* ad_h = AD + head * C;
  float ps = 0.f, pd = 0.f;
#pragma unroll
  for (int j = 0; j < EPL; j += 2) {
    const uint v = *(const uint*)(row + j);
    const float lo = bflo(v), hi = bfhi(v);
    ps += lo * as_h[cbase + j] + hi * as_h[cbase + j + 1];
    pd += lo * ad_h[cbase + j] + hi * ad_h[cbase + j + 1];
  }
#pragma unroll
  for (int off = 1; off < S; off <<= 1) {
    ps += __shfl_xor(ps, off);
    pd += __shfl_xor(pd, off);
  }
  if ((lane % S) == 0) {
    asb[n * H + head] = ps;
    adb[n * H + head] = pd;
  }
}

// ---------------- CSR scan (1024 threads, standalone: 20 rounds, ~10 us solo) ----------
__global__ __launch_bounds__(1024) void scan_kernel(const int* __restrict__ deg,
                                                    int* __restrict__ rowptr,
                                                    int* __restrict__ cursor, int n) {
  __shared__ int swsum[16];
  __shared__ int carry_s;
  const int t = threadIdx.x;
  const int wv = t >> 6, lane = t & 63;
  if (t == 0) carry_s = 0;
  __syncthreads();
  for (int base = 0; base < n; base += 1024) {
    const int i = base + t;
    const int v = (i < n) ? (deg[i] + 1) : 0;
    int sc = v;
#pragma unroll
    for (int off = 1; off < 64; off <<= 1) {
      const int u = __shfl_up(sc, off);
      if (lane >= off) sc += u;
    }
    if (lane == 63) swsum[wv] = sc;
    __syncthreads();
    if (t < 16) {
      int x = swsum[t];
#pragma unroll
      for (int off = 1; off < 16; off <<= 1) {
        const int u = __shfl_up(x, off);
        if (t >= off) x += u;
      }
      swsum[t] = x;
    }
    __syncthreads();
    const int incl = sc + (wv == 0 ? 0 : swsum[wv - 1]) + carry_s;
    if (i < n) { rowptr[i + 1] = incl; cursor[i] = incl - v; }
    if (base == 0 && t == 0) rowptr[0] = 0;
    __syncthreads();
    if (t == 0) carry_s += swsum[15];
    __syncthreads();
  }
}

// ---------------- wave-per-node softmax-weighted gather aggregate (output-space) -------
template <int H, int C>
__global__ __launch_bounds__(256) void gat_agg_wave(
    const ushort* __restrict__ hb, const int* __restrict__ rowptr,
    const int* __restrict__ csr_src, const float* __restrict__ a_s,
    const float* __restrict__ a_d, const float* __restrict__ bias,
    ushort* __restrict__ outb, float act_slope, int Nn) {
  constexpr int HC = H * C;
  constexpr int NU = HC / 2;
  constexpr int UPT = NU / 256;       // uint4 per lane
  constexpr int GRP = (UPT == 2) ? 4 : 8;
  const int n = blockIdx.x * 4 + (threadIdx.x >> 6);
  const int lane = threadIdx.x & 63;
  if (n >= Nn) return;
  float ad_n[H];
#pragma unroll
  for (int h = 0; h < H; h++) ad_n[h] = a_d[n * H + h];
  const int start = rowptr[n], end = rowptr[n + 1];
  f32x4 acc[UPT][2];
#pragma unroll
  for (int q = 0; q < UPT; q++)
#pragma unroll
    for (int u = 0; u < 2; u++)
#pragma unroll
      for (int e = 0; e < 4; e++) acc[q][u][e] = 0.f;
  float den[H];
#pragma unroll
  for (int h = 0; h < H; h++) den[h] = 0.f;

  for (int base = start; base < end; base += 64) {
    const int cnt = min(64, end - base);
    int s = 0;
    float w[H];
#pragma unroll
    for (int h = 0; h < H; h++) w[h] = 0.f;
    if (lane < cnt) {
      s = csr_src[base + lane];
      float asv[H];
      if constexpr (H == 4) {
        const float4 t4 = *(const float4*)(a_s + s * 4);
        asv[0] = t4.x; asv[1] = t4.y; asv[2] = t4.z; asv[3] = t4.w;
      } else {
        asv[0] = a_s[s];
      }
#pragma unroll
      for (int h = 0; h < H; h++) {
        float lg = asv[h] + ad_n[h];
        lg = LRELU(lg, 0.2f);
        w[h] = __expf(lg);
        den[h] += w[h];
      }
    }
    const int cntg = cnt & ~(GRP - 1);
    int j = 0;
    for (; j < cntg; j += GRP) {
      uint4 v[GRP][UPT];
#pragma unroll
      for (int g = 0; g < GRP; g++) {
        const int sj = __builtin_amdgcn_readlane(s, j + g);
        const uint4* hp = (const uint4*)(hb + (size_t)sj * HC);
#pragma unroll
        for (int q = 0; q < UPT; q++) v[g][q] = hp[q * 64 + lane];
      }
#pragma unroll
      for (int g = 0; g < GRP; g++) {
        float wj[H];
#pragma unroll
        for (int h = 0; h < H; h++) wj[h] = rl_f(w[h], j + g);
#pragma unroll
        for (int q = 0; q < UPT; q++) {
          const int e0 = q * 512 + 8 * lane;
          const float wq = wj[e0 / C];
          acc[q][0][0] += wq * bflo(v[g][q].x);
          acc[q][0][1] += wq * bfhi(v[g][q].x);
          acc[q][0][2] += wq * bflo(v[g][q].y);
          acc[q][0][3] += wq * bfhi(v[g][q].y);
          acc[q][1][0] += wq * bflo(v[g][q].z);
          acc[q][1][1] += wq * bfhi(v[g][q].z);
          acc[q][1][2] += wq * bflo(v[g][q].w);
          acc[q][1][3] += wq * bfhi(v[g][q].w);
        }
      }
    }
    for (; j < cnt; j++) {
      const int sj = __builtin_amdgcn_readlane(s, j);
      float wj[H];
#pragma unroll
      for (int h = 0; h < H; h++) wj[h] = rl_f(w[h], j);
      const uint4* hp = (const uint4*)(hb + (size_t)sj * HC);
#pragma unroll
      for (int q = 0; q < UPT; q++) {
        const int e0 = q * 512 + 8 * lane;
        const uint4 v = hp[q * 64 + lane];
        const float wq = wj[e0 / C];
        acc[q][0][0] += wq * bflo(v.x);
        acc[q][0][1] += wq * bfhi(v.x);
        acc[q][0][2] += wq * bflo(v.y);
        acc[q][0][3] += wq * bfhi(v.y);
        acc[q][1][0] += wq * bflo(v.z);
        acc[q][1][1] += wq * bfhi(v.z);
        acc[q][1][2] += wq * bflo(v.w);
        acc[q][1][3] += wq * bfhi(v.w);
      }
    }
  }
#pragma unroll
  for (int h = 0; h < H; h++) {
#pragma unroll
    for (int off = 1; off < 64; off <<= 1) den[h] += __shfl_xor(den[h], off);
    den[h] = 1.f / den[h];
  }
#pragma unroll
  for (int q = 0; q < UPT; q++) {
    const int e0 = q * 512 + 8 * lane;
    const float iv = den[e0 / C];
    const float4 ba = *(const float4*)(bias + e0);
    const float4 bb = *(const float4*)(bias + e0 + 4);
    const float o0 = LRELU(acc[q][0][0] * iv + ba.x, act_slope);
    const float o1 = LRELU(acc[q][0][1] * iv + ba.y, act_slope);
    const float o2 = LRELU(acc[q][0][2] * iv + ba.z, act_slope);
    const float o3 = LRELU(acc[q][0][3] * iv + ba.w, act_slope);
    const float o4 = LRELU(acc[q][1][0] * iv + bb.x, act_slope);
    const float o5 = LRELU(acc[q][1][1] * iv + bb.y, act_slope);
    const float o6 = LRELU(acc[q][1][2] * iv + bb.z, act_slope);
    const float o7 = LRELU(acc[q][1][3] * iv + bb.w, act_slope);
    uint4 o;
    o.x = (uint)f2bf(o0) | ((uint)f2bf(o1) << 16);
    o.y = (uint)f2bf(o2) | ((uint)f2bf(o3) << 16);
    o.z = (uint)f2bf(o4) | ((uint)f2bf(o5) << 16);
    o.w = (uint)f2bf(o6) | ((uint)f2bf(o7) << 16);
    ((uint4*)outb)[(size_t)n * (NU / 4) + q * 64 + lane] = o;
  }
}

// ---------------- layer-3 aggregate (H=1,C=128) fused with head MLP ------------------
__global__ __launch_bounds__(256) void gat_agg3_mlp(
    const ushort* __restrict__ hb, const int* __restrict__ rowptr,
    const int* __restrict__ csr_src, const float* __restrict__ a_s,
    const float* __restrict__ a_d, const float* __restrict__ b3,
    const float* __restrict__ pw, const float* __restrict__ pb,
    const float* __restrict__ f1w, const float* __restrict__ f1b,
    const float* __restrict__ f2w, const float* __restrict__ f2b,
    float* __restrict__ out, int Nn) {
  __shared__ float sx[4][128];
  __shared__ float s1[4][16];
  __shared__ float s2[4][32];
  const int w = threadIdx.x >> 6;
  const int lane = threadIdx.x & 63;
  const int n = blockIdx.x * 4 + w;
  if (n >= Nn) return;
  const float ad_n = a_d[n];
  const int start = rowptr[n], end = rowptr[n + 1];
  float2 acc = make_float2(0.f, 0.f);
  float den = 0.f;
  for (int base = start; base < end; base += 64) {
    const int cnt = min(64, end - base);
    int s = 0;
    float wv_ = 0.f;
    if (lane < cnt) {
      s = csr_src[base + lane];
      float lg = a_s[s] + ad_n;
      lg = LRELU(lg, 0.2f);
      wv_ = __expf(lg);
      den += wv_;
    }
    const int cntg = cnt & ~7;
    int j = 0;
    for (; j < cntg; j += 8) {
      uint v[8];
      float wj[8];
#pragma unroll
      for (int g = 0; g < 8; g++) {
        const int sj = __builtin_amdgcn_readlane(s, j + g);
        v[g] = ((const uint*)(hb + (size_t)sj * 128))[lane];
        wj[g] = rl_f(wv_, j + g);
      }
#pragma unroll
      for (int g = 0; g < 8; g++) {
        acc.x += wj[g] * bflo(v[g]);
        acc.y += wj[g] * bfhi(v[g]);
      }
    }
    for (; j < cnt; j++) {
      const int sj = __builtin_amdgcn_readlane(s, j);
      const float wj = rl_f(wv_, j);
      const uint v = ((const uint*)(hb + (size_t)sj * 128))[lane];
      acc.x += wj * bflo(v);
      acc.y += wj * bfhi(v);
    }
  }
#pragma unroll
  for (int off = 1; off < 64; off <<= 1) den += __shfl_xor(den, off);
  const float iv = 1.f / den;
  sx[w][2 * lane]     = LRELU(acc.x * iv + b3[2 * lane], 0.15f);
  sx[w][2 * lane + 1] = LRELU(acc.y * iv + b3[2 * lane + 1], 0.15f);
  {
    const int o = lane & 15, p = lane >> 4;
    float a = 0.f;
#pragma unroll
    for (int c = 0; c < 32; c++) a += sx[w][p * 32 + c] * pw[(p * 32 + c) * 16 + o];
    a += __shfl_xor(a, 16);
    a += __shfl_xor(a, 32);
    if (lane < 16) s1[w][o] = a + pb[o];
  }
  {
    const int o = lane & 31, p = lane >> 5;
    float a = 0.f;
#pragma unroll
    for (int c = 0; c < 8; c++) a += s1[w][p * 8 + c] * f1w[(p * 8 + c) * 32 + o];
    a += __shfl_xor(a, 32);
    if (lane < 32) s2[w][o] = LRELU(a + f1b[o], 0.15f);
  }
  {
    const int o = lane & 1, p = lane >> 1;
    float a = s2[w][p] * f2w[p * 2 + o];
    a += __shfl_xor(a, 2);
    a += __shfl_xor(a, 4);
    a += __shfl_xor(a, 8);
    a += __shfl_xor(a, 16);
    a += __shfl_xor(a, 32);
    if (lane < 2) out[(size_t)n * 2 + o] = a + f2b[o];
  }
}

extern "C" void kernel_launch(void* const* d_in, const int* in_sizes, int n_in,
                              void* d_out, int out_size, void* d_ws, size_t ws_size,
                              hipStream_t stream) {
  const float* x   = (const float*)d_in[0];
  const int* ei    = (const int*)d_in[1];
  const float* W1  = (const float*)d_in[2];
  const float* as1 = (const float*)d_in[3];
  const float* ad1 = (const float*)d_in[4];
  const float* b1  = (const float*)d_in[5];
  const float* W2  = (const float*)d_in[6];
  const float* as2 = (const float*)d_in[7];
  const float* ad2 = (const float*)d_in[8];
  const float* b2  = (const float*)d_in[9];
  const float* W3  = (const float*)d_in[10];
  const float* as3 = (const float*)d_in[11];
  const float* ad3 = (const float*)d_in[12];
  const float* b3  = (const float*)d_in[13];
  const float* pw  = (const float*)d_in[14];
  const float* pb  = (const float*)d_in[15];
  const float* f1w = (const float*)d_in[16];
  const float* f1b = (const float*)d_in[17];
  const float* f2w = (const float*)d_in[18];
  const float* f2b = (const float*)d_in[19];
  float* out = (float*)d_out;

  const int N = in_sizes[0] / 1287;   // 20000
  const int E = in_sizes[1] / 2;      // 160000
  const int Etot = E + N;
  const int* esrc = ei;
  const int* edst = ei + E;
  const int K1 = 1287, K1p = 1312;

  char* ws = (char*)d_ws;
  size_t off = 0;
  auto alloc = [&](size_t bytes) -> void* {
    void* p = ws + off;
    off = (off + bytes + 255) & ~(size_t)255;
    return p;
  };
  ushort* hb  = (ushort*)alloc((size_t)N * 1024 * 2);
  ushort* ob  = (ushort*)alloc((size_t)N * 1024 * 2);
  ushort* xb  = (ushort*)alloc((size_t)N * K1p * 2);
  ushort* W1t = (ushort*)alloc((size_t)512 * K1p * 2);
  ushort* W2t = (ushort*)alloc((size_t)1024 * 512 * 2);
  ushort* W3t = (ushort*)alloc((size_t)128 * 1024 * 2);
  float* av   = (float*)alloc((size_t)N * 8 * sizeof(float));  // a_s then a_d
  int* deg    = (int*)alloc((size_t)N * sizeof(int));
  int* rowptr = (int*)alloc((size_t)(N + 1) * sizeof(int));
  int* cursor = (int*)alloc((size_t)N * sizeof(int));
  int* csr    = (int*)alloc((size_t)Etot * sizeof(int));
  float* asb = av;
  float* adb = av + (size_t)N * 4;

  // ---- prep: deg zero (memset) + fused cast/transpose/count_deg ----
  hipMemsetAsync(deg, 0, (size_t)N * sizeof(int), stream);
  const int nA = (int)(((long long)N * (K1p / 8) + 255) / 256);  // 12813
  const int nB = (K1p / 32) * (512 / 32);                        // 656
  const int nC = (512 / 32) * (1024 / 32);                       // 512
  const int nD = (1024 / 32) * (128 / 32);                       // 128
  const int nCnt = (E + 255) / 256;                              // 625
  prep_all<<<nA + nB + nC + nD + nCnt, 256, 0, stream>>>(
      x, xb, W1, W1t, W2, W2t, W3, W3t,
      edst, deg, E, N, K1, K1p, nA, nB, nC, nD);

  scan_kernel<<<1, 1024, 0, stream>>>(deg, rowptr, cursor, N);

  const int tilesM = (N + 127) / 128;    // 157
  const int tilesM64 = (N + 63) / 64;    // 313
  const int nodeBlocks = (N + 3) / 4;    // 5000
  const int scatB = (Etot + 255) / 256;  // 704

  // ---- layer 1: gemm1 -> [dots1 || scatter] -> agg1 ----
  {
    const int g = tilesM * 4;  // 628 (3 blocks/CU -> single residency round)
    gemm_bf16<128, 1, true><<<g, 256, 0, stream>>>(xb, W1t, hb, N, 512, K1p, g);
    att_dots<4, 128><<<nodeBlocks + scatB, 256, 0, stream>>>(
        hb, as1, ad1, asb, adb, N, nodeBlocks, esrc, edst, E, Etot, cursor, csr);
    gat_agg_wave<4, 128><<<nodeBlocks, 256, 0, stream>>>(hb, rowptr, csr, asb, adb,
                                                         b1, ob, 0.15f, N);
  }
  // ---- layer 2: gemm2 (2-buffer: 5 blocks/CU) -> dots2 -> agg2 ----
  {
    const int g = tilesM * 8;  // 1256
    gemm_bf16<128, 2, false><<<g, 256, 0, stream>>>(ob, W2t, hb, N, 1024, 512, g);
    att_dots<4, 256><<<nodeBlocks, 256, 0, stream>>>(
        hb, as2, ad2, asb, adb, N, nodeBlocks, nullptr, nullptr, 0, 0, nullptr, nullptr);
    gat_agg_wave<4, 256><<<nodeBlocks, 256, 0, stream>>>(hb, rowptr, csr, asb, adb,
                                                         b2, ob, 0.15f, N);
  }
  // ---- layer 3: gemm3 -> dots3 -> agg3 + MLP ----
  {
    gemm_bf16<64, 3, true><<<tilesM64, 256, 0, stream>>>(ob, W3t, hb, N, 128, 1024,
                                                         tilesM64);
    att_dots<1, 128><<<nodeBlocks, 256, 0, stream>>>(
        hb, as3, ad3, asb, adb, N, nodeBlocks, nullptr, nullptr, 0, 0, nullptr, nullptr);
    gat_agg3_mlp<<<nodeBlocks, 256, 0, stream>>>(hb, rowptr, csr, asb, adb, b3,
                                                 pw, pb, f1w, f1b, f2w, f2b, out, N);
  }
}

// Round 15
// 440.531 us; speedup vs baseline: 1.0349x; 1.0216x over previous
//
#include <hip/hip_runtime.h>
#include <hip/hip_bf16.h>
#include <cstdint>
#include <cstddef>

#define LRELU(x, s) ((x) > 0.f ? (x) : (s) * (x))

typedef __attribute__((ext_vector_type(8))) short bf16x8;
typedef __attribute__((ext_vector_type(4))) float f32x4;

__device__ __forceinline__ float bflo(uint v) { return __uint_as_float(v << 16); }
__device__ __forceinline__ float bfhi(uint v) { return __uint_as_float(v & 0xffff0000u); }
__device__ __forceinline__ ushort f2bf(float f) {  // RTNE, finite inputs
  const uint u = __float_as_uint(f);
  return (ushort)((u + 0x7fffu + ((u >> 16) & 1u)) >> 16);
}
__device__ __forceinline__ float rl_f(float x, int j) {
  return __uint_as_float(__builtin_amdgcn_readlane(__float_as_uint(x), j));
}

// async global->LDS copy, 16 B per lane; LDS dest = wave-uniform base + lane*16.
__device__ __forceinline__ void async16(const ushort* g, ushort* l) {
  __builtin_amdgcn_global_load_lds(
      (const __attribute__((address_space(1))) unsigned int*)g,
      (__attribute__((address_space(3))) unsigned int*)l, 16, 0, 0);
}

// s_waitcnt immediates: vmcnt in [3:0], expcnt=7 (no wait), lgkmcnt=15 (no wait)
#define WAITCNT_VM(n) (0xF70 | (n))

// ---------------- fused prep: x cast+pad (8-wide), 3x W transpose-cast, count_deg ------
__global__ __launch_bounds__(256) void prep_all(
    const float* __restrict__ x, ushort* __restrict__ xb,
    const float* __restrict__ W1, ushort* __restrict__ W1t,
    const float* __restrict__ W2, ushort* __restrict__ W2t,
    const float* __restrict__ W3, ushort* __restrict__ W3t,
    const int* __restrict__ edst, int* __restrict__ deg, int E,
    int N, int K1, int K1p, int nA, int nB, int nC, int nD) {
  __shared__ float tile[32][33];
  const int tid = threadIdx.x;
  int b = blockIdx.x;
  if (b < nA) {  // x: fp32 -> bf16, 8 elems/thread, K padding
    const int P8 = K1p >> 3;   // 164
    const long long idx = (long long)b * 256 + tid;
    if (idx < (long long)N * P8) {
      const int r = (int)(idx / P8);
      const int c = ((int)(idx - (long long)r * P8)) << 3;
      const float* p = x + (size_t)r * K1 + c;
      float v[8];
      if (c + 7 < K1) {
        const float4 a = *(const float4*)p;
        const float4 bq = *(const float4*)(p + 4);
        v[0] = a.x; v[1] = a.y; v[2] = a.z; v[3] = a.w;
        v[4] = bq.x; v[5] = bq.y; v[6] = bq.z; v[7] = bq.w;
      } else {
#pragma unroll
        for (int j = 0; j < 8; j++) v[j] = (c + j < K1) ? p[j] : 0.f;
      }
      uint4 o;
      o.x = (uint)f2bf(v[0]) | ((uint)f2bf(v[1]) << 16);
      o.y = (uint)f2bf(v[2]) | ((uint)f2bf(v[3]) << 16);
      o.z = (uint)f2bf(v[4]) | ((uint)f2bf(v[5]) << 16);
      o.w = (uint)f2bf(v[6]) | ((uint)f2bf(v[7]) << 16);
      *(uint4*)(xb + (size_t)r * K1p + c) = o;
    }
    return;
  }
  b -= nA;
  if (b < nB + nC + nD) {  // W transpose-casts
    const float* W; ushort* Wt; int K, Nn, Kp, tilesK;
    if (b < nB)           { W = W1; Wt = W1t; K = K1;   Nn = 512;  Kp = K1p;  tilesK = K1p / 32; }
    else if (b < nB + nC) { b -= nB; W = W2; Wt = W2t; K = 512;  Nn = 1024; Kp = 512;  tilesK = 16; }
    else                  { b -= nB + nC; W = W3; Wt = W3t; K = 1024; Nn = 128; Kp = 1024; tilesK = 32; }
    const int kt = (b % tilesK) * 32;
    const int nt = (b / tilesK) * 32;
    const int tx = tid & 31, ty = tid >> 5;
    for (int r = ty; r < 32; r += 8) {
      const int k = kt + r, nn = nt + tx;
      tile[r][tx] = (k < K && nn < Nn) ? W[(size_t)k * Nn + nn] : 0.f;
    }
    __syncthreads();
    for (int r = ty; r < 32; r += 8) {
      const int nn = nt + r, k = kt + tx;
      if (nn < Nn && k < Kp) Wt[(size_t)nn * Kp + k] = f2bf(tile[tx][r]);
    }
    return;
  }
  b -= nB + nC + nD;
  {  // count_deg (deg pre-zeroed by memset)
    const int t = b * 256 + tid;
    if (t < E) atomicAdd(&deg[edst[t]], 1);
  }
}

// ---------------- bf16 MFMA GEMM ------------------------------------------------------
// BUF3=true : 3-buffer, single barrier per K-step (48KB LDS, 3 blocks/CU).
// BUF3=false: 2-buffer, two barriers per K-step (32KB LDS, 5 blocks/CU) — layer 2.
// Blocks >= gemmBlocks run scatter_edges (layer-1 launch only; scan in prior launch;
// scatter hides under the long GEMM host, measured best placement).
template <int TM, int TAG, bool BUF3>
__global__ __launch_bounds__(256) void gemm_bf16(
    const ushort* __restrict__ A, const ushort* __restrict__ Bt, ushort* __restrict__ C,
    int M, int N, int Kp, int gemmBlocks,
    const int* __restrict__ esrc, const int* __restrict__ edst, int E, int Etot,
    int* __restrict__ cursor, int* __restrict__ csr_src) {
  constexpr int MI = TM / 32;               // mi-tiles per wave (4 or 2)
  constexpr int LPG = (TM == 128) ? 4 : 3;  // loads per group per lane
  constexpr int NBUF = BUF3 ? 3 : 2;
  __shared__ ushort sA[NBUF * TM * 32];
  __shared__ ushort sB[NBUF * 128 * 32];
  const int tid = threadIdx.x;
  const int wave = tid >> 6;
  const int lane = tid & 63;

  if (blockIdx.x >= gemmBlocks) {  // scatter (scan completed in a prior launch)
    const int t = (blockIdx.x - gemmBlocks) * 256 + tid;
    if (t >= Etot) return;
    int s, d;
    if (t < E) { s = esrc[t]; d = edst[t]; } else { s = t - E; d = s; }
    const int pos = atomicAdd(&cursor[d], 1);
    csr_src[pos] = s;
    return;
  }

  const int tilesN = N >> 7;
  // bijective XCD-aware remap (works sharing an A row-panel land on one XCD)
  const int nwg = gemmBlocks;
  const int q8 = nwg >> 3, r8 = nwg & 7;
  const int xcd = blockIdx.x & 7;
  const int lid = blockIdx.x >> 3;
  const int wg = (xcd < r8 ? xcd * (q8 + 1) : r8 * (q8 + 1) + (xcd - r8) * q8) + lid;
  const int bx = wg % tilesN;
  const int by = wg / tilesN;
  const int wrow = (wave >> 1) * (TM / 2);
  const int wcol = (wave & 1) * 64;
  const int quad = lane >> 4;
  const int ml = lane & 15;

  const int seg = (((lane & 3) ^ ((lane >> 3) & 3)) * 8);
  const int rB0 = wave * 32 + (lane >> 2);
  const int gB0 = bx * 128 + rB0;
  const ushort* pB0 = Bt + (size_t)gB0 * Kp + seg;
  const ushort* pB1 = Bt + (size_t)(gB0 + 16) * Kp + seg;
  ushort* lB0 = &sB[(wave * 32) * 32];
  ushort* lB1 = &sB[(wave * 32 + 16) * 32];
  const ushort *pA0, *pA1;
  ushort *lA0, *lA1;
  if constexpr (TM == 128) {
    const int r0 = wave * 32 + (lane >> 2);
    pA0 = A + (size_t)min(by * TM + r0, M - 1) * Kp + seg;
    pA1 = A + (size_t)min(by * TM + r0 + 16, M - 1) * Kp + seg;
    lA0 = &sA[(wave * 32) * 32];
    lA1 = &sA[(wave * 32 + 16) * 32];
  } else {
    const int r0 = wave * 16 + (lane >> 2);
    pA0 = A + (size_t)min(by * TM + r0, M - 1) * Kp + seg;
    pA1 = nullptr;
    lA0 = &sA[(wave * 16) * 32];
    lA1 = nullptr;
  }

  const int nIter = Kp >> 5;
  auto issue = [&](int it, int p) {
    const int k0 = it << 5;
    const int oa = p * TM * 32;
    const int ob_ = p * 128 * 32;
    async16(pA0 + k0, lA0 + oa);
    if constexpr (TM == 128) async16(pA1 + k0, lA1 + oa);
    async16(pB0 + k0, lB0 + ob_);
    async16(pB1 + k0, lB1 + ob_);
  };

  f32x4 acc[MI][4];
#pragma unroll
  for (int mi = 0; mi < MI; mi++)
#pragma unroll
    for (int ni = 0; ni < 4; ni++)
#pragma unroll
      for (int e = 0; e < 4; e++) acc[mi][ni][e] = 0.f;

  const int rq = (quad ^ ((ml >> 1) & 3)) * 8;  // un-swizzle for fragment reads

  issue(0, 0);
  if (nIter > 1) issue(1, 1);
  int b = 0;
  for (int it = 0; it < nIter; ++it) {
    if (it + 1 < nIter) __builtin_amdgcn_s_waitcnt(WAITCNT_VM(LPG));
    else __builtin_amdgcn_s_waitcnt(WAITCNT_VM(0));
    __builtin_amdgcn_s_barrier();
    if constexpr (BUF3) {
      if (it + 2 < nIter) {
        const int b2 = (b + 2 >= 3) ? b - 1 : b + 2;  // = (it+2)%3, holds tile it-1 (free)
        issue(it + 2, b2);
      }
    }
    const ushort* bA = &sA[b * TM * 32];
    const ushort* bB = &sB[b * 128 * 32];
    bf16x8 af[MI], bfr[4];
#pragma unroll
    for (int mi = 0; mi < MI; mi++)
      af[mi] = *(const bf16x8*)&bA[(wrow + mi * 16 + ml) * 32 + rq];
#pragma unroll
    for (int ni = 0; ni < 4; ni++)
      bfr[ni] = *(const bf16x8*)&bB[(wcol + ni * 16 + ml) * 32 + rq];
#pragma unroll
    for (int mi = 0; mi < MI; mi++)
#pragma unroll
      for (int ni = 0; ni < 4; ni++)
        acc[mi][ni] = __builtin_amdgcn_mfma_f32_16x16x32_bf16(af[mi], bfr[ni], acc[mi][ni], 0, 0, 0);
    if constexpr (!BUF3) {
      if (it + 2 < nIter) {
        __builtin_amdgcn_s_barrier();  // all waves done reading buf b
        issue(it + 2, b);
      }
      b ^= 1;
    } else {
      b = (b + 1 == 3) ? 0 : b + 1;
    }
  }

  // C write (bf16)
#pragma unroll
  for (int mi = 0; mi < MI; mi++) {
#pragma unroll
    for (int r = 0; r < 4; r++) {
      const int row = by * TM + wrow + mi * 16 + quad * 4 + r;
      if (row < M) {
#pragma unroll
        for (int ni = 0; ni < 4; ni++) {
          const int col = bx * 128 + wcol + ni * 16 + ml;
          C[(size_t)row * N + col] = f2bf(acc[mi][ni][r]);
        }
      }
    }
  }
}

// ---------------- attention dots, h-side: asb/adb[n,h] = dot(hb[n,h*C:..], AS/AD[h]) ---
template <int H, int C>
__global__ __launch_bounds__(256) void att_dots(
    const ushort* __restrict__ hb, const float* __restrict__ AS,
    const float* __restrict__ AD, float* __restrict__ asb, float* __restrict__ adb,
    int Nn) {
  constexpr int HC = H * C;
  constexpr int EPL = HC / 64;
  constexpr int S = C / EPL;
  const int n = blockIdx.x * 4 + (threadIdx.x >> 6);
  const int lane = threadIdx.x & 63;
  if (n >= Nn) return;
  const int head = lane / S;
  const int cbase = (lane % S) * EPL;
  const ushort* row = hb + (size_t)n * HC + lane * EPL;
  const float* as_h = AS + head * C;
  const float* ad_h = AD + head * C;
  float ps = 0.f, pd = 0.f;
#pragma unroll
  for (int j = 0; j < EPL; j += 2) {
    const uint v = *(const uint*)(row + j);
    const float lo = bflo(v), hi = bfhi(v);
    ps += lo * as_h[cbase + j] + hi * as_h[cbase + j + 1];
    pd += lo * ad_h[cbase + j] + hi * ad_h[cbase + j + 1];
  }
#pragma unroll
  for (int off = 1; off < S; off <<= 1) {
    ps += __shfl_xor(ps, off);
    pd += __shfl_xor(pd, off);
  }
  if ((lane % S) == 0) {
    asb[n * H + head] = ps;
    adb[n * H + head] = pd;
  }
}

// ---------------- CSR scan (1024 threads, standalone) ----------------
__global__ __launch_bounds__(1024) void scan_kernel(const int* __restrict__ deg,
                                                    int* __restrict__ rowptr,
                                                    int* __restrict__ cursor, int n) {
  __shared__ int swsum[16];
  __shared__ int carry_s;
  const int t = threadIdx.x;
  const int wv = t >> 6, lane = t & 63;
  if (t == 0) carry_s = 0;
  __syncthreads();
  for (int base = 0; base < n; base += 1024) {
    const int i = base + t;
    const int v = (i < n) ? (deg[i] + 1) : 0;
    int sc = v;
#pragma unroll
    for (int off = 1; off < 64; off <<= 1) {
      const int u = __shfl_up(sc, off);
      if (lane >= off) sc += u;
    }
    if (lane == 63) swsum[wv] = sc;
    __syncthreads();
    if (t < 16) {
      int x = swsum[t];
#pragma unroll
      for (int off = 1; off < 16; off <<= 1) {
        const int u = __shfl_up(x, off);
        if (t >= off) x += u;
      }
      swsum[t] = x;
    }
    __syncthreads();
    const int incl = sc + (wv == 0 ? 0 : swsum[wv - 1]) + carry_s;
    if (i < n) { rowptr[i + 1] = incl; cursor[i] = incl - v; }
    if (base == 0 && t == 0) rowptr[0] = 0;
    __syncthreads();
    if (t == 0) carry_s += swsum[15];
    __syncthreads();
  }
}

// ---------------- wave-per-node softmax-weighted gather aggregate (output-space) -------
template <int H, int C>
__global__ __launch_bounds__(256) void gat_agg_wave(
    const ushort* __restrict__ hb, const int* __restrict__ rowptr,
    const int* __restrict__ csr_src, const float* __restrict__ a_s,
    const float* __restrict__ a_d, const float* __restrict__ bias,
    ushort* __restrict__ outb, float act_slope, int Nn) {
  constexpr int HC = H * C;
  constexpr int NU = HC / 2;
  constexpr int UPT = NU / 256;       // uint4 per lane
  constexpr int GRP = (UPT == 2) ? 4 : 8;
  const int n = blockIdx.x * 4 + (threadIdx.x >> 6);
  const int lane = threadIdx.x & 63;
  if (n >= Nn) return;
  float ad_n[H];
#pragma unroll
  for (int h = 0; h < H; h++) ad_n[h] = a_d[n * H + h];
  const int start = rowptr[n], end = rowptr[n + 1];
  f32x4 acc[UPT][2];
#pragma unroll
  for (int q = 0; q < UPT; q++)
#pragma unroll
    for (int u = 0; u < 2; u++)
#pragma unroll
      for (int e = 0; e < 4; e++) acc[q][u][e] = 0.f;
  float den[H];
#pragma unroll
  for (int h = 0; h < H; h++) den[h] = 0.f;

  for (int base = start; base < end; base += 64) {
    const int cnt = min(64, end - base);
    int s = 0;
    float w[H];
#pragma unroll
    for (int h = 0; h < H; h++) w[h] = 0.f;
    if (lane < cnt) {
      s = csr_src[base + lane];
      float asv[H];
      if constexpr (H == 4) {
        const float4 t4 = *(const float4*)(a_s + s * 4);
        asv[0] = t4.x; asv[1] = t4.y; asv[2] = t4.z; asv[3] = t4.w;
      } else {
        asv[0] = a_s[s];
      }
#pragma unroll
      for (int h = 0; h < H; h++) {
        float lg = asv[h] + ad_n[h];
        lg = LRELU(lg, 0.2f);
        w[h] = __expf(lg);
        den[h] += w[h];
      }
    }
    const int cntg = cnt & ~(GRP - 1);
    int j = 0;
    for (; j < cntg; j += GRP) {
      uint4 v[GRP][UPT];
#pragma unroll
      for (int g = 0; g < GRP; g++) {
        const int sj = __builtin_amdgcn_readlane(s, j + g);
        const uint4* hp = (const uint4*)(hb + (size_t)sj * HC);
#pragma unroll
        for (int q = 0; q < UPT; q++) v[g][q] = hp[q * 64 + lane];
      }
#pragma unroll
      for (int g = 0; g < GRP; g++) {
        float wj[H];
#pragma unroll
        for (int h = 0; h < H; h++) wj[h] = rl_f(w[h], j + g);
#pragma unroll
        for (int q = 0; q < UPT; q++) {
          const int e0 = q * 512 + 8 * lane;
          const float wq = wj[e0 / C];
          acc[q][0][0] += wq * bflo(v[g][q].x);
          acc[q][0][1] += wq * bfhi(v[g][q].x);
          acc[q][0][2] += wq * bflo(v[g][q].y);
          acc[q][0][3] += wq * bfhi(v[g][q].y);
          acc[q][1][0] += wq * bflo(v[g][q].z);
          acc[q][1][1] += wq * bfhi(v[g][q].z);
          acc[q][1][2] += wq * bflo(v[g][q].w);
          acc[q][1][3] += wq * bfhi(v[g][q].w);
        }
      }
    }
    for (; j < cnt; j++) {
      const int sj = __builtin_amdgcn_readlane(s, j);
      float wj[H];
#pragma unroll
      for (int h = 0; h < H; h++) wj[h] = rl_f(w[h], j);
      const uint4* hp = (const uint4*)(hb + (size_t)sj * HC);
#pragma unroll
      for (int q = 0; q < UPT; q++) {
        const int e0 = q * 512 + 8 * lane;
        const uint4 v = hp[q * 64 + lane];
        const float wq = wj[e0 / C];
        acc[q][0][0] += wq * bflo(v.x);
        acc[q][0][1] += wq * bfhi(v.x);
        acc[q][0][2] += wq * bflo(v.y);
        acc[q][0][3] += wq * bfhi(v.y);
        acc[q][1][0] += wq * bflo(v.z);
        acc[q][1][1] += wq * bfhi(v.z);
        acc[q][1][2] += wq * bflo(v.w);
        acc[q][1][3] += wq * bfhi(v.w);
      }
    }
  }
#pragma unroll
  for (int h = 0; h < H; h++) {
#pragma unroll
    for (int off = 1; off < 64; off <<= 1) den[h] += __shfl_xor(den[h], off);
    den[h] = 1.f / den[h];
  }
#pragma unroll
  for (int q = 0; q < UPT; q++) {
    const int e0 = q * 512 + 8 * lane;
    const float iv = den[e0 / C];
    const float4 ba = *(const float4*)(bias + e0);
    const float4 bb = *(const float4*)(bias + e0 + 4);
    const float o0 = LRELU(acc[q][0][0] * iv + ba.x, act_slope);
    const float o1 = LRELU(acc[q][0][1] * iv + ba.y, act_slope);
    const float o2 = LRELU(acc[q][0][2] * iv + ba.z, act_slope);
    const float o3 = LRELU(acc[q][0][3] * iv + ba.w, act_slope);
    const float o4 = LRELU(acc[q][1][0] * iv + bb.x, act_slope);
    const float o5 = LRELU(acc[q][1][1] * iv + bb.y, act_slope);
    const float o6 = LRELU(acc[q][1][2] * iv + bb.z, act_slope);
    const float o7 = LRELU(acc[q][1][3] * iv + bb.w, act_slope);
    uint4 o;
    o.x = (uint)f2bf(o0) | ((uint)f2bf(o1) << 16);
    o.y = (uint)f2bf(o2) | ((uint)f2bf(o3) << 16);
    o.z = (uint)f2bf(o4) | ((uint)f2bf(o5) << 16);
    o.w = (uint)f2bf(o6) | ((uint)f2bf(o7) << 16);
    ((uint4*)outb)[(size_t)n * (NU / 4) + q * 64 + lane] = o;
  }
}

// ---------------- layer-3 aggregate (H=1,C=128) fused with head MLP ------------------
__global__ __launch_bounds__(256) void gat_agg3_mlp(
    const ushort* __restrict__ hb, const int* __restrict__ rowptr,
    const int* __restrict__ csr_src, const float* __restrict__ a_s,
    const float* __restrict__ a_d, const float* __restrict__ b3,
    const float* __restrict__ pw, const float* __restrict__ pb,
    const float* __restrict__ f1w, const float* __restrict__ f1b,
    const float* __restrict__ f2w, const float* __restrict__ f2b,
    float* __restrict__ out, int Nn) {
  __shared__ float sx[4][128];
  __shared__ float s1[4][16];
  __shared__ float s2[4][32];
  const int w = threadIdx.x >> 6;
  const int lane = threadIdx.x & 63;
  const int n = blockIdx.x * 4 + w;
  if (n >= Nn) return;
  const float ad_n = a_d[n];
  const int start = rowptr[n], end = rowptr[n + 1];
  float2 acc = make_float2(0.f, 0.f);
  float den = 0.f;
  for (int base = start; base < end; base += 64) {
    const int cnt = min(64, end - base);
    int s = 0;
    float wv_ = 0.f;
    if (lane < cnt) {
      s = csr_src[base + lane];
      float lg = a_s[s] + ad_n;
      lg = LRELU(lg, 0.2f);
      wv_ = __expf(lg);
      den += wv_;
    }
    const int cntg = cnt & ~7;
    int j = 0;
    for (; j < cntg; j += 8) {
      uint v[8];
      float wj[8];
#pragma unroll
      for (int g = 0; g < 8; g++) {
        const int sj = __builtin_amdgcn_readlane(s, j + g);
        v[g] = ((const uint*)(hb + (size_t)sj * 128))[lane];
        wj[g] = rl_f(wv_, j + g);
      }
#pragma unroll
      for (int g = 0; g < 8; g++) {
        acc.x += wj[g] * bflo(v[g]);
        acc.y += wj[g] * bfhi(v[g]);
      }
    }
    for (; j < cnt; j++) {
      const int sj = __builtin_amdgcn_readlane(s, j);
      const float wj = rl_f(wv_, j);
      const uint v = ((const uint*)(hb + (size_t)sj * 128))[lane];
      acc.x += wj * bflo(v);
      acc.y += wj * bfhi(v);
    }
  }
#pragma unroll
  for (int off = 1; off < 64; off <<= 1) den += __shfl_xor(den, off);
  const float iv = 1.f / den;
  sx[w][2 * lane]     = LRELU(acc.x * iv + b3[2 * lane], 0.15f);
  sx[w][2 * lane + 1] = LRELU(acc.y * iv + b3[2 * lane + 1], 0.15f);
  {
    const int o = lane & 15, p = lane >> 4;
    float a = 0.f;
#pragma unroll
    for (int c = 0; c < 32; c++) a += sx[w][p * 32 + c] * pw[(p * 32 + c) * 16 + o];
    a += __shfl_xor(a, 16);
    a += __shfl_xor(a, 32);
    if (lane < 16) s1[w][o] = a + pb[o];
  }
  {
    const int o = lane & 31, p = lane >> 5;
    float a = 0.f;
#pragma unroll
    for (int c = 0; c < 8; c++) a += s1[w][p * 8 + c] * f1w[(p * 8 + c) * 32 + o];
    a += __shfl_xor(a, 32);
    if (lane < 32) s2[w][o] = LRELU(a + f1b[o], 0.15f);
  }
  {
    const int o = lane & 1, p = lane >> 1;
    float a = s2[w][p] * f2w[p * 2 + o];
    a += __shfl_xor(a, 2);
    a += __shfl_xor(a, 4);
    a += __shfl_xor(a, 8);
    a += __shfl_xor(a, 16);
    a += __shfl_xor(a, 32);
    if (lane < 2) out[(size_t)n * 2 + o] = a + f2b[o];
  }
}

extern "C" void kernel_launch(void* const* d_in, const int* in_sizes, int n_in,
                              void* d_out, int out_size, void* d_ws, size_t ws_size,
                              hipStream_t stream) {
  const float* x   = (const float*)d_in[0];
  const int* ei    = (const int*)d_in[1];
  const float* W1  = (const float*)d_in[2];
  const float* as1 = (const float*)d_in[3];
  const float* ad1 = (const float*)d_in[4];
  const float* b1  = (const float*)d_in[5];
  const float* W2  = (const float*)d_in[6];
  const float* as2 = (const float*)d_in[7];
  const float* ad2 = (const float*)d_in[8];
  const float* b2  = (const float*)d_in[9];
  const float* W3  = (const float*)d_in[10];
  const float* as3 = (const float*)d_in[11];
  const float* ad3 = (const float*)d_in[12];
  const float* b3  = (const float*)d_in[13];
  const float* pw  = (const float*)d_in[14];
  const float* pb  = (const float*)d_in[15];
  const float* f1w = (const float*)d_in[16];
  const float* f1b = (const float*)d_in[17];
  const float* f2w = (const float*)d_in[18];
  const float* f2b = (const float*)d_in[19];
  float* out = (float*)d_out;

  const int N = in_sizes[0] / 1287;   // 20000
  const int E = in_sizes[1] / 2;      // 160000
  const int Etot = E + N;
  const int* esrc = ei;
  const int* edst = ei + E;
  const int K1 = 1287, K1p = 1312;

  char* ws = (char*)d_ws;
  size_t off = 0;
  auto alloc = [&](size_t bytes) -> void* {
    void* p = ws + off;
    off = (off + bytes + 255) & ~(size_t)255;
    return p;
  };
  ushort* hb  = (ushort*)alloc((size_t)N * 1024 * 2);
  ushort* ob  = (ushort*)alloc((size_t)N * 1024 * 2);
  ushort* xb  = (ushort*)alloc((size_t)N * K1p * 2);
  ushort* W1t = (ushort*)alloc((size_t)512 * K1p * 2);
  ushort* W2t = (ushort*)alloc((size_t)1024 * 512 * 2);
  ushort* W3t = (ushort*)alloc((size_t)128 * 1024 * 2);
  float* av   = (float*)alloc((size_t)N * 8 * sizeof(float));  // a_s then a_d
  int* deg    = (int*)alloc((size_t)N * sizeof(int));
  int* rowptr = (int*)alloc((size_t)(N + 1) * sizeof(int));
  int* cursor = (int*)alloc((size_t)N * sizeof(int));
  int* csr    = (int*)alloc((size_t)Etot * sizeof(int));
  float* asb = av;
  float* adb = av + (size_t)N * 4;

  // ---- prep: deg zero (memset) + fused cast/transpose/count_deg ----
  hipMemsetAsync(deg, 0, (size_t)N * sizeof(int), stream);
  const int nA = (int)(((long long)N * (K1p / 8) + 255) / 256);  // 12813
  const int nB = (K1p / 32) * (512 / 32);                        // 656
  const int nC = (512 / 32) * (1024 / 32);                       // 512
  const int nD = (1024 / 32) * (128 / 32);                       // 128
  const int nCnt = (E + 255) / 256;                              // 625
  prep_all<<<nA + nB + nC + nD + nCnt, 256, 0, stream>>>(
      x, xb, W1, W1t, W2, W2t, W3, W3t,
      edst, deg, E, N, K1, K1p, nA, nB, nC, nD);

  scan_kernel<<<1, 1024, 0, stream>>>(deg, rowptr, cursor, N);

  const int tilesM = (N + 127) / 128;    // 157
  const int tilesM64 = (N + 63) / 64;    // 313
  const int nodeBlocks = (N + 3) / 4;    // 5000
  const int scatB = (Etot + 255) / 256;  // 704

  // ---- layer 1: [gemm1 || scatter] -> dots1 -> agg1 ----
  {
    const int g = tilesM * 4;  // 628 (3 blocks/CU -> single residency round)
    gemm_bf16<128, 1, true><<<g + scatB, 256, 0, stream>>>(
        xb, W1t, hb, N, 512, K1p, g, esrc, edst, E, Etot, cursor, csr);
    att_dots<4, 128><<<nodeBlocks, 256, 0, stream>>>(hb, as1, ad1, asb, adb, N);
    gat_agg_wave<4, 128><<<nodeBlocks, 256, 0, stream>>>(hb, rowptr, csr, asb, adb,
                                                         b1, ob, 0.15f, N);
  }
  // ---- layer 2: gemm2 (2-buffer: 5 blocks/CU) -> dots2 -> agg2 ----
  {
    const int g = tilesM * 8;  // 1256
    gemm_bf16<128, 2, false><<<g, 256, 0, stream>>>(
        ob, W2t, hb, N, 1024, 512, g, nullptr, nullptr, 0, 0, nullptr, nullptr);
    att_dots<4, 256><<<nodeBlocks, 256, 0, stream>>>(hb, as2, ad2, asb, adb, N);
    gat_agg_wave<4, 256><<<nodeBlocks, 256, 0, stream>>>(hb, rowptr, csr, asb, adb,
                                                         b2, ob, 0.15f, N);
  }
  // ---- layer 3: gemm3 -> dots3 -> agg3 + MLP ----
  {
    gemm_bf16<64, 3, true><<<tilesM64, 256, 0, stream>>>(
        ob, W3t, hb, N, 128, 1024, tilesM64, nullptr, nullptr, 0, 0, nullptr, nullptr);
    att_dots<1, 128><<<nodeBlocks, 256, 0, stream>>>(hb, as3, ad3, asb, adb, N);
    gat_agg3_mlp<<<nodeBlocks, 256, 0, stream>>>(hb, rowptr, csr, asb, adb, b3,
                                                 pw, pb, f1w, f1b, f2w, f2b, out, N);
  }
}